// Round 8
// baseline (225.975 us; speedup 1.0000x reference)
//
#include <hip/hip_runtime.h>
#include <hip/hip_bf16.h>

// DepConv3D, pipelined persistent-tile version, R8.
//   diff = depth[nbr]-depth[center]; kd=0 iff diff==-1, kd=1 iff diff==0, else 0.
// Structure (from R7): 256 blocks (1/CU), NT=4 tiles each, double-buffered
// 2x68 KB LDS, T14 issue-early/write-late pipeline.
// R8 changes vs R7 (82 us; VGPR=108 proves compiler SANK the prefetch loads
// to write_tile — pf[48] can't be live in 108 regs):
//   - sched_barrier(0) after issue(): loads pinned above compute, pf held
//     live across it (prefetch actually in flight under MFMA).
//   - it-loop unrolled x2: two independent acc chains per wave -> 2x ds_read
//     and MFMA streams in flight (2 waves/SIMD alone can't hide LDS+MFMA
//     latency; MfmaUtil 9%, VALUBusy 22%, ~70% issue-idle).
// __launch_bounds__(512, 1): VGPR cap 256. Est. usage ~195. (512,4) capped
// at 64 -> R2 spill disaster; watch WRITE_SIZE (>140 MB = spill, revert).
// Tile = 4 rows x 256 px, staged as 6x258 halo (bf16 pixel-major, 40 B padded
// px stride -> conflict-free b64 LDS; int depth with SENT for out-of-image).
// MFMA 16x16x32_bf16 (validated): 1st op m=lane&15, kk=(lane>>4)*8+j;
// D: col=lane&15 (oc), row=(lane>>4)*4+r (pixel) -> dwordx4 stores.

#define IC 16
#define OC 32
#define Hh 512
#define Ww 512
#define HW (Hh * Ww)
#define TW 256          // tile width  (output px)
#define TR 4            // tile rows   (output)
#define PXS 20          // shorts per px in LDS (40 B, padded from 32)
#define SENT (1 << 20)  // sentinel depth: diff never in {0,-1}
#define NT 4            // tiles per block; grid = 1024/NT = 256

typedef __attribute__((ext_vector_type(8))) short short8;
typedef __attribute__((ext_vector_type(4))) float float4v;
typedef __attribute__((ext_vector_type(2))) unsigned int uint2v;

__device__ __forceinline__ unsigned short f2bf(float x) {
    unsigned u = __float_as_uint(x);
    unsigned r = u + 0x7FFFu + ((u >> 16) & 1u);   // RNE
    return (unsigned short)(r >> 16);
}

// packed RNE pair via v_cvt_pk_bf16_f32 (compiler fuses _rn cast pairs)
__device__ __forceinline__ unsigned packbf(float a, float b) {
    union { __hip_bfloat162 h2; unsigned u; } cv;
    cv.h2 = __float22bfloat162_rn(make_float2(a, b));
    return cv.u;
}

// ---- prepass: fp32 weights (32,16,3,3,3) -> bf16 fragments (2nd-operand) ----
__global__ void prep_weights(const float* __restrict__ wgt,
                             unsigned short* __restrict__ wsA) {
    int e = blockIdx.x * 256 + threadIdx.x;
    if (e >= 9 * 2 * 64 * 8) return;
    int j    = e & 7;
    int lane = (e >> 3) & 63;
    int mt   = (e >> 9) & 1;
    int c    = e >> 10;
    int oc = mt * 16 + (lane & 15);
    int kk = ((lane >> 4) << 3) + j;
    wsA[e] = f2bf(wgt[oc * 432 + (kk >> 1) * 27 + (kk & 1) * 9 + c]);
}

// ---- fused main kernel: 4-tile pipeline, double-buffered LDS ----
__global__ __launch_bounds__(512, 1) void depconv_fused(
    const float* __restrict__ feat,           // (4,16,512,512) fp32
    const int*   __restrict__ depth,          // (4,512,512)
    const unsigned short* __restrict__ wsA,
    float*       __restrict__ out)            // (4,32,512,512)
{
    __shared__ unsigned short ftile[2][6][TW + 2][PXS];   // 123,840 B
    __shared__ int            dtile[2][6][TW + 2];        //  12,384 B

    const int tid = threadIdx.x;
    const int bid = blockIdx.x;
    // XCD swizzle: 256 blocks, 8 XCDs -> XCD x gets contiguous wg [32x,32x+31]
    const int wg = (bid & 7) * 32 + (bid >> 3);
    const int t0 = wg * NT;

    // staging roles
    const int h8 = tid >> 8;           // ic-half: ics 8*h8..8*h8+7 (wave-uniform)
    const int xl = tid & 255;          // tile x (body px)

    // compute roles
    const int lane = tid & 63;
    const int wv   = tid >> 6;
    const int g    = lane >> 4;        // ic-group for A-build: ics 4g..4g+3
    const int n    = lane & 15;        // A-operand pixel (m = lane&15)
    const int rr   = wv >> 1;          // output row within tile: 0..3
    const int xoff = (wv & 1) * 128;
    const int q    = lane >> 4;        // store: pixel quad 4q..4q+3
    const int oc0  = lane & 15;        // store: oc plane

    // weight fragments (global, L2-broadcast)
    short8 wfrag[9][2];
    {
        const short8* ap = (const short8*)wsA;
#pragma unroll
        for (int c = 0; c < 9; ++c) {
            wfrag[c][0] = ap[(c * 2 + 0) * 64 + lane];
            wfrag[c][1] = ap[(c * 2 + 1) * 64 + lane];
        }
    }

    float pf[6][8];   // in-flight staging floats (issued early, used late)
    int   pd[6];      // in-flight depth (h8==0 threads)

    // ---- issue: fire tile tt's body global loads into pf/pd ----
    auto issue = [&](int tt) {
        const int b      = tt >> 8;
        const int h0     = ((tt >> 1) & 127) * TR;
        const int wstart = (tt & 1) * TW;
        const int x   = wstart - 1 + xl;
        const bool xin = (unsigned)x < (unsigned)Ww;
        const int xc  = x < 0 ? 0 : (x > Ww - 1 ? Ww - 1 : x);
        const float* fb  = feat + (size_t)(b * IC + 8 * h8) * HW + xc;
        const int*   dbp = depth + (b << 18) + xc;
#pragma unroll
        for (int r = 0; r < 6; ++r) {
            const int y = h0 - 1 + r;
            const bool yin = (unsigned)y < (unsigned)Hh;
            const int yc = y < 0 ? 0 : (y > Hh - 1 ? Hh - 1 : y);
            const float* fpl = fb + (size_t)yc * Ww;
            if (h8 == 0) pd[r] = (yin & xin) ? dbp[yc * Ww] : SENT;
#pragma unroll
            for (int i = 0; i < 8; ++i)
                pf[r][i] = fpl[(size_t)i * HW];
        }
    };

    // ---- write: convert pf -> LDS buf p; tail px (256,257) loaded here ----
    auto write_tile = [&](int p, int tt) {
        const int b      = tt >> 8;
        const int h0     = ((tt >> 1) & 127) * TR;
        const int wstart = (tt & 1) * TW;
#pragma unroll
        for (int r = 0; r < 6; ++r) {
            if (h8 == 0) dtile[p][r][xl] = pd[r];
            unsigned short* wp = &ftile[p][r][xl][h8 * 8];
            *(uint2v*)wp       = (uint2v){packbf(pf[r][0], pf[r][1]),
                                          packbf(pf[r][2], pf[r][3])};
            *(uint2v*)(wp + 4) = (uint2v){packbf(pf[r][4], pf[r][5]),
                                          packbf(pf[r][6], pf[r][7])};
        }
        if (xl < 2) {   // 4 threads: tail pixels, loaded directly (tiny)
            const int xt = wstart - 1 + 256 + xl;
            const bool xtin = (unsigned)xt < (unsigned)Ww;
            const int xct = xt > Ww - 1 ? Ww - 1 : xt;
            const float* fb  = feat + (size_t)(b * IC + 8 * h8) * HW + xct;
            const int*   dbp = depth + (b << 18) + xct;
#pragma unroll
            for (int r = 0; r < 6; ++r) {
                const int y = h0 - 1 + r;
                const bool yin = (unsigned)y < (unsigned)Hh;
                const int yc = y < 0 ? 0 : (y > Hh - 1 ? Hh - 1 : y);
                const float* fpl = fb + (size_t)yc * Ww;
                if (h8 == 0)
                    dtile[p][r][256 + xl] = (yin & xtin) ? dbp[yc * Ww] : SENT;
                unsigned short* wq = &ftile[p][r][256 + xl][h8 * 8];
                *(uint2v*)wq       = (uint2v){packbf(fpl[0],              fpl[(size_t)1 * HW]),
                                              packbf(fpl[(size_t)2 * HW], fpl[(size_t)3 * HW])};
                *(uint2v*)(wq + 4) = (uint2v){packbf(fpl[(size_t)4 * HW], fpl[(size_t)5 * HW]),
                                              packbf(fpl[(size_t)6 * HW], fpl[(size_t)7 * HW])};
            }
        }
    };

    // ---- compute tile tt from buf p: 2 its jointly (dual acc chains) ----
    auto compute = [&](int p, int tt) {
        const int b      = tt >> 8;
        const int h0     = ((tt >> 1) & 127) * TR;
        const int wstart = (tt & 1) * TW;
        const int h = h0 + rr;
        float* opb0 = out + ((size_t)(b * OC + oc0) << 18) + (size_t)h * Ww;
#pragma unroll 1
        for (int it = 0; it < 8; it += 2) {
            const int xbA = xoff + it * 16 + n;
            const int xbB = xbA + 16;
            const int dcA = dtile[p][rr + 1][xbA + 1];
            const int dcB = dtile[p][rr + 1][xbB + 1];
            float4v a0A = {0.f, 0.f, 0.f, 0.f};
            float4v a1A = {0.f, 0.f, 0.f, 0.f};
            float4v a0B = {0.f, 0.f, 0.f, 0.f};
            float4v a1B = {0.f, 0.f, 0.f, 0.f};
#pragma unroll
            for (int t = 0; t < 9; ++t) {
                const int kh = t / 3, kw = t % 3;
                unsigned mmA, mmB;
                if (t == 4) {
                    mmA = mmB = 0xffff0000u;   // center: diff==0, kd=1 slice
                } else {
                    const int dfA = dtile[p][rr + kh][xbA + kw] - dcA;
                    mmA = (dfA == 0) ? 0xffff0000u : ((dfA == -1) ? 0x0000ffffu : 0u);
                    const int dfB = dtile[p][rr + kh][xbB + kw] - dcB;
                    mmB = (dfB == 0) ? 0xffff0000u : ((dfB == -1) ? 0x0000ffffu : 0u);
                }
                const uint2v prA = *(const uint2v*)(&ftile[p][rr + kh][xbA + kw][g << 2]);
                const uint2v prB = *(const uint2v*)(&ftile[p][rr + kh][xbB + kw][g << 2]);
                union { short8 s; unsigned u[4]; } bfA, bfB;
                bfA.u[0] = __builtin_amdgcn_perm(0u, prA.x, 0x01000100u) & mmA;
                bfA.u[1] = __builtin_amdgcn_perm(0u, prA.x, 0x03020302u) & mmA;
                bfA.u[2] = __builtin_amdgcn_perm(0u, prA.y, 0x01000100u) & mmA;
                bfA.u[3] = __builtin_amdgcn_perm(0u, prA.y, 0x03020302u) & mmA;
                bfB.u[0] = __builtin_amdgcn_perm(0u, prB.x, 0x01000100u) & mmB;
                bfB.u[1] = __builtin_amdgcn_perm(0u, prB.x, 0x03020302u) & mmB;
                bfB.u[2] = __builtin_amdgcn_perm(0u, prB.y, 0x01000100u) & mmB;
                bfB.u[3] = __builtin_amdgcn_perm(0u, prB.y, 0x03020302u) & mmB;

                // features as A (M=pixels), weights as B (N=oc)
                a0A = __builtin_amdgcn_mfma_f32_16x16x32_bf16(bfA.s, wfrag[t][0], a0A, 0, 0, 0);
                a1A = __builtin_amdgcn_mfma_f32_16x16x32_bf16(bfA.s, wfrag[t][1], a1A, 0, 0, 0);
                a0B = __builtin_amdgcn_mfma_f32_16x16x32_bf16(bfB.s, wfrag[t][0], a0B, 0, 0, 0);
                a1B = __builtin_amdgcn_mfma_f32_16x16x32_bf16(bfB.s, wfrag[t][1], a1B, 0, 0, 0);
            }
            // lane stores px w16+4q..+3 of plane oc0 (acc0) / oc0+16 (acc1)
            const int w16A = wstart + xoff + it * 16;
            float* opA = opb0 + (w16A + 4 * q);
            *(float4v*)opA                     = a0A;
            *(float4v*)(opA + (size_t)16 * HW) = a1A;
            float* opB = opA + 16;
            *(float4v*)opB                     = a0B;
            *(float4v*)(opB + (size_t)16 * HW) = a1B;
        }
    };

    // ---- pipelined main loop ----
    issue(t0);
    write_tile(0, t0);
    __syncthreads();
#pragma unroll 1
    for (int i = 0; i < NT; ++i) {
        const int p = i & 1;
        if (i + 1 < NT) {
            issue(t0 + i + 1);                       // loads in flight...
            __builtin_amdgcn_sched_barrier(0);       // ...pinned above compute
        }
        compute(p, t0 + i);
        if (i + 1 < NT) {
            write_tile(p ^ 1, t0 + i + 1);           // vmcnt drains here
            __syncthreads();
        }
    }
}

extern "C" void kernel_launch(void* const* d_in, const int* in_sizes, int n_in,
                              void* d_out, int out_size, void* d_ws, size_t ws_size,
                              hipStream_t stream) {
    const float* feat  = (const float*)d_in[0];
    const int*   depth = (const int*)d_in[1];
    const float* wgt   = (const float*)d_in[2];
    float* out = (float*)d_out;

    unsigned short* wsA = (unsigned short*)d_ws;     // 18,432 B only

    prep_weights<<<36, 256, 0, stream>>>(wgt, wsA);
    depconv_fused<<<256, 512, 0, stream>>>(feat, depth, wsA, out);
}

// Round 9
// 209.278 us; speedup vs baseline: 1.0798x; 1.0798x over previous
//
#include <hip/hip_runtime.h>
#include <hip/hip_bf16.h>

// DepConv3D, producer/consumer wave-specialized version, R9.
//   diff = depth[nbr]-depth[center]; kd=0 iff diff==-1, kd=1 iff diff==0, else 0.
// R7/R8 lesson: register-pipelined prefetch is defeated by the allocator
// (VGPR 108/128 can't hold pf[48] live; loads sink to their use). Fix by
// STRUCTURE, not scheduling: 768 threads = 8 consumer waves (R7's proven
// compute layout) + 4 producer waves. While consumers compute tile i from
// LDS buf[i&1], producers load+convert+ds_write tile i+1 into buf[i^1].
// Producer load latency is hidden by co-resident consumer MFMA waves (m114
// co-issue), with zero live-across-compute registers needed.
// 256 blocks (1/CU), NT=4 tiles each, double-buffered 2x68 KB LDS.
// __launch_bounds__(768, 1): 12 waves = 3/SIMD -> VGPR cap 170; union of
// producer(~40)/consumer(~110) paths ~120. Watch WRITE_SIZE >142 MB = spill.
// Tile = 4 rows x 256 px, staged as 6x258 halo (bf16 pixel-major, 40 B padded
// px stride -> conflict-free b64 LDS; int depth with SENT for out-of-image).
// MFMA 16x16x32_bf16 (validated): 1st op m=lane&15, kk=(lane>>4)*8+j;
// D: col=lane&15 (oc), row=(lane>>4)*4+r (pixel) -> dwordx4 stores.

#define IC 16
#define OC 32
#define Hh 512
#define Ww 512
#define HW (Hh * Ww)
#define TW 256          // tile width  (output px)
#define TR 4            // tile rows   (output)
#define PXS 20          // shorts per px in LDS (40 B, padded from 32)
#define SENT (1 << 20)  // sentinel depth: diff never in {0,-1}
#define NT 4            // tiles per block; grid = 1024/NT = 256

typedef __attribute__((ext_vector_type(8))) short short8;
typedef __attribute__((ext_vector_type(4))) float float4v;
typedef __attribute__((ext_vector_type(2))) unsigned int uint2v;

__device__ __forceinline__ unsigned short f2bf(float x) {
    unsigned u = __float_as_uint(x);
    unsigned r = u + 0x7FFFu + ((u >> 16) & 1u);   // RNE
    return (unsigned short)(r >> 16);
}

// packed RNE pair via v_cvt_pk_bf16_f32 (compiler fuses _rn cast pairs)
__device__ __forceinline__ unsigned packbf(float a, float b) {
    union { __hip_bfloat162 h2; unsigned u; } cv;
    cv.h2 = __float22bfloat162_rn(make_float2(a, b));
    return cv.u;
}

// ---- prepass: fp32 weights (32,16,3,3,3) -> bf16 fragments (2nd-operand) ----
__global__ void prep_weights(const float* __restrict__ wgt,
                             unsigned short* __restrict__ wsA) {
    int e = blockIdx.x * 256 + threadIdx.x;
    if (e >= 9 * 2 * 64 * 8) return;
    int j    = e & 7;
    int lane = (e >> 3) & 63;
    int mt   = (e >> 9) & 1;
    int c    = e >> 10;
    int oc = mt * 16 + (lane & 15);
    int kk = ((lane >> 4) << 3) + j;
    wsA[e] = f2bf(wgt[oc * 432 + (kk >> 1) * 27 + (kk & 1) * 9 + c]);
}

// ---- fused main kernel: producer/consumer waves, double-buffered LDS ----
__global__ __launch_bounds__(768, 1) void depconv_fused(
    const float* __restrict__ feat,           // (4,16,512,512) fp32
    const int*   __restrict__ depth,          // (4,512,512)
    const unsigned short* __restrict__ wsA,
    float*       __restrict__ out)            // (4,32,512,512)
{
    __shared__ unsigned short ftile[2][6][TW + 2][PXS];   // 123,840 B
    __shared__ int            dtile[2][6][TW + 2];        //  12,384 B

    const int tid = threadIdx.x;
    const int bid = blockIdx.x;
    // XCD swizzle: 256 blocks, 8 XCDs -> XCD x gets contiguous wg [32x,32x+31]
    const int wg = (bid & 7) * 32 + (bid >> 3);
    const int t0 = wg * NT;

    const bool isProd = (tid >= 512);
    const int  xl     = tid - 512;     // producer: body px [0,256)

    // consumer roles (garbage-but-unused for producer threads)
    const int lane = tid & 63;
    const int wv   = tid >> 6;
    const int g    = lane >> 4;        // ic-group for A-build: ics 4g..4g+3
    const int n    = lane & 15;        // A-operand pixel (m = lane&15)
    const int rr   = wv >> 1;          // output row within tile: 0..3
    const int xoff = (wv & 1) * 128;
    const int q    = lane >> 4;        // store: pixel quad 4q..4q+3
    const int oc0  = lane & 15;        // store: oc plane

    // weight fragments (consumers only; loads overlap producer prologue)
    short8 wfrag[9][2];
    if (!isProd) {
        const short8* ap = (const short8*)wsA;
#pragma unroll
        for (int c = 0; c < 9; ++c) {
            wfrag[c][0] = ap[(c * 2 + 0) * 64 + lane];
            wfrag[c][1] = ap[(c * 2 + 1) * 64 + lane];
        }
    }

    // ---- producer: load + convert + LDS-write tile tt into buf p ----
    auto stage = [&](int p, int tt) {
        const int b      = tt >> 8;
        const int h0     = ((tt >> 1) & 127) * TR;
        const int wstart = (tt & 1) * TW;
        const int x   = wstart - 1 + xl;
        const bool xin = (unsigned)x < (unsigned)Ww;
        const int xc  = x < 0 ? 0 : (x > Ww - 1 ? Ww - 1 : x);
        const float* fb  = feat + (size_t)b * IC * HW + xc;
        const int*   dbp = depth + (b << 18) + xc;
#pragma unroll
        for (int r = 0; r < 6; ++r) {
            const int y = h0 - 1 + r;
            const bool yin = (unsigned)y < (unsigned)Hh;
            const int yc = y < 0 ? 0 : (y > Hh - 1 ? Hh - 1 : y);
            const float* fpl = fb + (size_t)yc * Ww;
            dtile[p][r][xl] = (yin & xin) ? dbp[yc * Ww] : SENT;
            unsigned pk[8];
#pragma unroll
            for (int i = 0; i < 8; ++i)
                pk[i] = packbf(fpl[(size_t)(2 * i) * HW],
                               fpl[(size_t)(2 * i + 1) * HW]);
            unsigned short* wp = &ftile[p][r][xl][0];
            *(uint2v*)(wp)      = (uint2v){pk[0], pk[1]};
            *(uint2v*)(wp + 4)  = (uint2v){pk[2], pk[3]};
            *(uint2v*)(wp + 8)  = (uint2v){pk[4], pk[5]};
            *(uint2v*)(wp + 12) = (uint2v){pk[6], pk[7]};
        }
        // tail px 256,257: 12 threads, one (row, px) pair each
        const int ti = xl - 128;
        if ((unsigned)ti < 12u) {
            const int r  = ti >> 1;
            const int tp = ti & 1;
            const int xt = wstart - 1 + 256 + tp;
            const bool xtin = (unsigned)xt < (unsigned)Ww;
            const int xct = xt > Ww - 1 ? Ww - 1 : xt;
            const int y = h0 - 1 + r;
            const bool yin = (unsigned)y < (unsigned)Hh;
            const int yc = y < 0 ? 0 : (y > Hh - 1 ? Hh - 1 : y);
            const float* fpl = feat + (size_t)b * IC * HW + (size_t)yc * Ww + xct;
            dtile[p][r][256 + tp] = (yin & xtin) ? depth[(b << 18) + yc * Ww + xct]
                                                 : SENT;
            unsigned qk[8];
#pragma unroll
            for (int i = 0; i < 8; ++i)
                qk[i] = packbf(fpl[(size_t)(2 * i) * HW],
                               fpl[(size_t)(2 * i + 1) * HW]);
            unsigned short* wq = &ftile[p][r][256 + tp][0];
            *(uint2v*)(wq)      = (uint2v){qk[0], qk[1]};
            *(uint2v*)(wq + 4)  = (uint2v){qk[2], qk[3]};
            *(uint2v*)(wq + 8)  = (uint2v){qk[4], qk[5]};
            *(uint2v*)(wq + 12) = (uint2v){qk[6], qk[7]};
        }
    };

    // ---- consumer: compute tile tt from buf p (R7's proven body) ----
    auto compute = [&](int p, int tt) {
        const int b      = tt >> 8;
        const int h0     = ((tt >> 1) & 127) * TR;
        const int wstart = (tt & 1) * TW;
        const int h = h0 + rr;
        float* opb0 = out + ((size_t)(b * OC + oc0) << 18) + (size_t)h * Ww;
#pragma unroll 1
        for (int it = 0; it < 8; ++it) {
            const int xb = xoff + it * 16 + n;
            const int dc = dtile[p][rr + 1][xb + 1];
            float4v acc0 = {0.f, 0.f, 0.f, 0.f};
            float4v acc1 = {0.f, 0.f, 0.f, 0.f};
#pragma unroll
            for (int t = 0; t < 9; ++t) {
                const int kh = t / 3, kw = t % 3;
                unsigned mm;
                if (t == 4) {
                    mm = 0xffff0000u;   // center: diff==0 always, kd=1 slice
                } else {
                    const int diff = dtile[p][rr + kh][xb + kw] - dc;
                    mm = (diff == 0) ? 0xffff0000u : ((diff == -1) ? 0x0000ffffu : 0u);
                }
                const uint2v pr = *(const uint2v*)(&ftile[p][rr + kh][xb + kw][g << 2]);
                union { short8 s; unsigned u[4]; } bf;
                bf.u[0] = __builtin_amdgcn_perm(0u, pr.x, 0x01000100u) & mm;  // ic 4g+0
                bf.u[1] = __builtin_amdgcn_perm(0u, pr.x, 0x03020302u) & mm;  // ic 4g+1
                bf.u[2] = __builtin_amdgcn_perm(0u, pr.y, 0x01000100u) & mm;  // ic 4g+2
                bf.u[3] = __builtin_amdgcn_perm(0u, pr.y, 0x03020302u) & mm;  // ic 4g+3

                // features as A (M=pixels), weights as B (N=oc)
                acc0 = __builtin_amdgcn_mfma_f32_16x16x32_bf16(bf.s, wfrag[t][0], acc0, 0, 0, 0);
                acc1 = __builtin_amdgcn_mfma_f32_16x16x32_bf16(bf.s, wfrag[t][1], acc1, 0, 0, 0);
            }
            // lane stores px w16+4q..+3 of plane oc0 (acc0) / oc0+16 (acc1)
            const int w16 = wstart + xoff + it * 16;
            float* op = opb0 + (w16 + 4 * q);
            *(float4v*)op                     = acc0;
            *(float4v*)(op + (size_t)16 * HW) = acc1;
        }
    };

    // ---- pipelined main loop: producers one tile ahead of consumers ----
    if (isProd) stage(0, t0);
    __syncthreads();
#pragma unroll 1
    for (int i = 0; i < NT; ++i) {
        if (!isProd) {
            compute(i & 1, t0 + i);
        } else if (i + 1 < NT) {
            stage((i + 1) & 1, t0 + i + 1);
        }
        __syncthreads();
    }
}

extern "C" void kernel_launch(void* const* d_in, const int* in_sizes, int n_in,
                              void* d_out, int out_size, void* d_ws, size_t ws_size,
                              hipStream_t stream) {
    const float* feat  = (const float*)d_in[0];
    const int*   depth = (const int*)d_in[1];
    const float* wgt   = (const float*)d_in[2];
    float* out = (float*)d_out;

    unsigned short* wsA = (unsigned short*)d_ws;     // 18,432 B only

    prep_weights<<<36, 256, 0, stream>>>(wgt, wsA);
    depconv_fused<<<256, 768, 0, stream>>>(feat, depth, wsA, out);
}